// Round 2
// baseline (7876.146 us; speedup 1.0000x reference)
//
#include <hip/hip_runtime.h>
#include <hip/hip_bf16.h>
#include <hip/hip_fp16.h>

typedef __attribute__((ext_vector_type(8))) short s16x8;
typedef __attribute__((ext_vector_type(8))) _Float16 f16x8;
typedef __attribute__((ext_vector_type(4))) float f32x4;

// ---------------------------------------------------------------------------
// fp32 -> fp16 conversion (vectorized, grid-stride)
// ---------------------------------------------------------------------------
__global__ void cvt_f32_to_f16_kernel(const float* __restrict__ in,
                                      __half* __restrict__ out,
                                      long n) {
  long i = (long)blockIdx.x * blockDim.x + threadIdx.x;
  long stride = (long)gridDim.x * blockDim.x;
  const float4* p4 = (const float4*)in;
  for (long j = i; j * 8 < n; j += stride) {
    float4 a = p4[j * 2];
    float4 b = p4[j * 2 + 1];
    union { s16x8 v; __half2 h2[4]; } w;
    w.h2[0] = __floats2half2_rn(a.x, a.y);
    w.h2[1] = __floats2half2_rn(a.z, a.w);
    w.h2[2] = __floats2half2_rn(b.x, b.y);
    w.h2[3] = __floats2half2_rn(b.z, b.w);
    *(s16x8*)(out + j * 8) = w.v;
  }
}

// ---------------------------------------------------------------------------
// Dequant 8 int4-in-int32 values -> 8 fp16 weights via bit-trick + pk_fma.
// f16(64+q) = 0x5400 | (q<<4);  w = b*s - (64+z)*s  (one v_pk_fma_f16 / pair)
// ---------------------------------------------------------------------------
__device__ __forceinline__ void dq_store(const int* __restrict__ qp,
                                         __half2 s2, __half2 c2,
                                         __half* __restrict__ dst) {
  int4 q0 = *(const int4*)qp;
  int4 q1 = *(const int4*)(qp + 4);
  uint32_t b0 = 0x54005400u + ((uint32_t)q0.x << 4) + ((uint32_t)q0.y << 20);
  uint32_t b1 = 0x54005400u + ((uint32_t)q0.z << 4) + ((uint32_t)q0.w << 20);
  uint32_t b2 = 0x54005400u + ((uint32_t)q1.x << 4) + ((uint32_t)q1.y << 20);
  uint32_t b3 = 0x54005400u + ((uint32_t)q1.z << 4) + ((uint32_t)q1.w << 20);
  union { s16x8 v; __half2 h2[4]; } w;
  w.h2[0] = __hfma2(*(__half2*)&b0, s2, c2);
  w.h2[1] = __hfma2(*(__half2*)&b1, s2, c2);
  w.h2[2] = __hfma2(*(__half2*)&b2, s2, c2);
  w.h2[3] = __hfma2(*(__half2*)&b3, s2, c2);
  *(s16x8*)dst = w.v;
}

__device__ __forceinline__ __half2 mk_s2(float s) {
  __half h = __float2half(s);
  return __halves2half2(h, h);
}
__device__ __forceinline__ __half2 mk_c2(float s, float z) {
  __half h = __float2half(-(64.f + z) * s);
  return __halves2half2(h, h);
}

// ---------------------------------------------------------------------------
// Fused gate+up GEMM: h = silu(x @ Wg^T) * (x @ Wu^T), fp16 MFMA, T2 swizzle.
// Tile: BM=128, BN=128, BK=64 (group loop of 128). 4 waves, 64x64 each.
// ---------------------------------------------------------------------------
__global__ __launch_bounds__(256, 2)
void gateup_kernel(const __half* __restrict__ Xh,
                   const int* __restrict__ Qg, const int* __restrict__ Qu,
                   const float* __restrict__ Sg, const float* __restrict__ Zg,
                   const float* __restrict__ Su, const float* __restrict__ Zu,
                   __half* __restrict__ Hout,
                   int mblocks) {
  constexpr int H = 4096, I = 11008, G = 32;
  const int bid = blockIdx.x;
  const int nb = bid / mblocks;
  const int mb = bid - nb * mblocks;
  const int m0 = mb * 128, n0 = nb * 128;
  const int tid = threadIdx.x;
  const int lane = tid & 63;
  const int wave = tid >> 6;
  const int wm = (wave >> 1) * 64, wn = (wave & 1) * 64;
  const int l15 = lane & 15, lq = lane >> 4;
  const int rsw = (l15 & 7) << 3;  // read-side swizzle

  __shared__ __half As[128][64];
  __shared__ __half Bgs[128][64];
  __shared__ __half Bus[128][64];

  f32x4 accg[4][4], accu[4][4];
#pragma unroll
  for (int i = 0; i < 4; ++i)
#pragma unroll
    for (int j = 0; j < 4; ++j) {
      accg[i][j] = {0.f, 0.f, 0.f, 0.f};
      accu[i][j] = {0.f, 0.f, 0.f, 0.f};
    }

  const int arow = tid >> 3;             // 0..31
  const int acol = (tid & 7) * 8;        // logical column (elements)
  const int swcol = acol ^ ((arow & 7) << 3);  // swizzled column

  for (int k0 = 0; k0 < H; k0 += 128) {
    const int gidx = k0 >> 7;
    // group-constant scale/zero per staging row
    __half2 s2g[4], c2g[4], s2u[4], c2u[4];
#pragma unroll
    for (int it = 0; it < 4; ++it) {
      const int rg = n0 + it * 32 + arow;
      float sgv = Sg[rg * G + gidx], zgv = Zg[rg * G + gidx];
      float suv = Su[rg * G + gidx], zuv = Zu[rg * G + gidx];
      s2g[it] = mk_s2(sgv); c2g[it] = mk_c2(sgv, zgv);
      s2u[it] = mk_s2(suv); c2u[it] = mk_c2(suv, zuv);
    }
#pragma unroll
    for (int half = 0; half < 2; ++half) {
      const int kk0 = k0 + half * 64;
      __syncthreads();
      // ---- stage A: global_load_lds, linear LDS dest + swizzled source ----
#pragma unroll
      for (int c = 0; c < 4; ++c) {
        const __half* src = Xh + (size_t)(m0 + c * 32 + arow) * H + (kk0 + swcol);
        __half* dst = &As[0][0] + (size_t)(c * 256 + tid) * 8;
        __builtin_amdgcn_global_load_lds((const __attribute__((address_space(1))) void*)src,
                                         (__attribute__((address_space(3))) void*)dst,
                                         16, 0, 0);
      }
      // ---- stage B: load q, dequant, swizzled ds_write ----
#pragma unroll
      for (int it = 0; it < 4; ++it) {
        const int r = it * 32 + arow;
        const int rg = n0 + r;
        dq_store(Qg + (size_t)rg * H + (kk0 + acol), s2g[it], c2g[it], &Bgs[r][swcol]);
        dq_store(Qu + (size_t)rg * H + (kk0 + acol), s2u[it], c2u[it], &Bus[r][swcol]);
      }
      __syncthreads();
      // ---- MFMA over BK=64 (two K=32 steps) ----
#pragma unroll
      for (int kk = 0; kk < 2; ++kk) {
        const int cbase = (kk * 32 + lq * 8) ^ rsw;
        f16x8 af[4], bgf[4], buf_[4];
#pragma unroll
        for (int i = 0; i < 4; ++i)
          af[i] = *(const f16x8*)&As[wm + i * 16 + l15][cbase];
#pragma unroll
        for (int j = 0; j < 4; ++j) {
          bgf[j]  = *(const f16x8*)&Bgs[wn + j * 16 + l15][cbase];
          buf_[j] = *(const f16x8*)&Bus[wn + j * 16 + l15][cbase];
        }
#pragma unroll
        for (int i = 0; i < 4; ++i)
#pragma unroll
          for (int j = 0; j < 4; ++j) {
            accg[i][j] = __builtin_amdgcn_mfma_f32_16x16x32_f16(af[i], bgf[j], accg[i][j], 0, 0, 0);
            accu[i][j] = __builtin_amdgcn_mfma_f32_16x16x32_f16(af[i], buf_[j], accu[i][j], 0, 0, 0);
          }
      }
    }
  }
  // ---- epilogue: h = silu(g)*u -> fp16 ----
#pragma unroll
  for (int i = 0; i < 4; ++i)
#pragma unroll
    for (int j = 0; j < 4; ++j)
#pragma unroll
      for (int r = 0; r < 4; ++r) {
        const int row = m0 + wm + i * 16 + lq * 4 + r;
        const int col = n0 + wn + j * 16 + l15;
        float g = accg[i][j][r];
        float u = accu[i][j][r];
        float hv = (g / (1.f + __expf(-g))) * u;
        Hout[(size_t)row * I + col] = __float2half(hv);
      }
}

// ---------------------------------------------------------------------------
// Down GEMM: out = h @ Wd^T. fp16 MFMA, T2 swizzle. K=11008.
// ---------------------------------------------------------------------------
__global__ __launch_bounds__(256, 2)
void down_kernel(const __half* __restrict__ Hin,
                 const int* __restrict__ Qd,
                 const float* __restrict__ Sd, const float* __restrict__ Zd,
                 float* __restrict__ Out,
                 int mblocks) {
  constexpr int K = 11008, N = 4096, G = 86;
  const int bid = blockIdx.x;
  const int nb = bid / mblocks;
  const int mb = bid - nb * mblocks;
  const int m0 = mb * 128, n0 = nb * 128;
  const int tid = threadIdx.x;
  const int lane = tid & 63;
  const int wave = tid >> 6;
  const int wm = (wave >> 1) * 64, wn = (wave & 1) * 64;
  const int l15 = lane & 15, lq = lane >> 4;
  const int rsw = (l15 & 7) << 3;

  __shared__ __half As[128][64];
  __shared__ __half Bs[128][64];

  f32x4 acc[4][4];
#pragma unroll
  for (int i = 0; i < 4; ++i)
#pragma unroll
    for (int j = 0; j < 4; ++j) acc[i][j] = {0.f, 0.f, 0.f, 0.f};

  const int arow = tid >> 3;
  const int acol = (tid & 7) * 8;
  const int swcol = acol ^ ((arow & 7) << 3);

  for (int k0 = 0; k0 < K; k0 += 128) {
    const int gidx = k0 >> 7;
    __half2 s2d[4], c2d[4];
#pragma unroll
    for (int it = 0; it < 4; ++it) {
      const int rg = n0 + it * 32 + arow;
      float sv = Sd[rg * G + gidx], zv = Zd[rg * G + gidx];
      s2d[it] = mk_s2(sv); c2d[it] = mk_c2(sv, zv);
    }
#pragma unroll
    for (int half = 0; half < 2; ++half) {
      const int kk0 = k0 + half * 64;
      __syncthreads();
#pragma unroll
      for (int c = 0; c < 4; ++c) {
        const __half* src = Hin + (size_t)(m0 + c * 32 + arow) * K + (kk0 + swcol);
        __half* dst = &As[0][0] + (size_t)(c * 256 + tid) * 8;
        __builtin_amdgcn_global_load_lds((const __attribute__((address_space(1))) void*)src,
                                         (__attribute__((address_space(3))) void*)dst,
                                         16, 0, 0);
      }
#pragma unroll
      for (int it = 0; it < 4; ++it) {
        const int r = it * 32 + arow;
        const int rg = n0 + r;
        dq_store(Qd + (size_t)rg * K + (kk0 + acol), s2d[it], c2d[it], &Bs[r][swcol]);
      }
      __syncthreads();
#pragma unroll
      for (int kk = 0; kk < 2; ++kk) {
        const int cbase = (kk * 32 + lq * 8) ^ rsw;
        f16x8 af[4], bf[4];
#pragma unroll
        for (int i = 0; i < 4; ++i)
          af[i] = *(const f16x8*)&As[wm + i * 16 + l15][cbase];
#pragma unroll
        for (int j = 0; j < 4; ++j)
          bf[j] = *(const f16x8*)&Bs[wn + j * 16 + l15][cbase];
#pragma unroll
        for (int i = 0; i < 4; ++i)
#pragma unroll
          for (int j = 0; j < 4; ++j)
            acc[i][j] = __builtin_amdgcn_mfma_f32_16x16x32_f16(af[i], bf[j], acc[i][j], 0, 0, 0);
      }
    }
  }
#pragma unroll
  for (int i = 0; i < 4; ++i)
#pragma unroll
    for (int j = 0; j < 4; ++j)
#pragma unroll
      for (int r = 0; r < 4; ++r) {
        const int row = m0 + wm + i * 16 + lq * 4 + r;
        const int col = n0 + wn + j * 16 + l15;
        Out[(size_t)row * N + col] = acc[i][j][r];
      }
}

// ---------------------------------------------------------------------------
extern "C" void kernel_launch(void* const* d_in, const int* in_sizes, int n_in,
                              void* d_out, int out_size, void* d_ws, size_t ws_size,
                              hipStream_t stream) {
  const float* x  = (const float*)d_in[0];
  const int* qg   = (const int*)d_in[1];
  const int* qu   = (const int*)d_in[2];
  const int* qd   = (const int*)d_in[3];
  const float* sg = (const float*)d_in[4];
  const float* zg = (const float*)d_in[5];
  const float* su = (const float*)d_in[6];
  const float* zu = (const float*)d_in[7];
  const float* sd = (const float*)d_in[8];
  const float* zd = (const float*)d_in[9];
  float* out = (float*)d_out;

  const int M = 4 * 2048, H = 4096, I = 11008;

  const size_t per_row = (size_t)(H + I) * 2;
  long mc = (long)(ws_size / per_row);
  mc &= ~127L;
  if (mc > M) mc = M;
  if (mc < 128) mc = 128;
  const int Mc = (int)mc;

  __half* wsx = (__half*)d_ws;
  __half* wsh = (__half*)((char*)d_ws + (size_t)Mc * H * 2);

  for (int mbase = 0; mbase < M; mbase += Mc) {
    const int rows = (M - mbase < Mc) ? (M - mbase) : Mc;
    const int mblocks = rows / 128;
    const long n = (long)rows * H;
    cvt_f32_to_f16_kernel<<<1024, 256, 0, stream>>>(x + (size_t)mbase * H, wsx, n);
    gateup_kernel<<<(I / 128) * mblocks, 256, 0, stream>>>(
        wsx, qg, qu, sg, zg, su, zu, wsh, mblocks);
    down_kernel<<<(H / 128) * mblocks, 256, 0, stream>>>(
        wsh, qd, sd, zd, out + (size_t)mbase * H, mblocks);
  }
}

// Round 3
// 5696.057 us; speedup vs baseline: 1.3827x; 1.3827x over previous
//
#include <hip/hip_runtime.h>
#include <hip/hip_bf16.h>
#include <hip/hip_fp16.h>

typedef __attribute__((ext_vector_type(8))) short s16x8;
typedef __attribute__((ext_vector_type(8))) _Float16 f16x8;
typedef __attribute__((ext_vector_type(4))) float f32x4;

// ---------------------------------------------------------------------------
// fp32 -> fp16 conversion (vectorized, grid-stride)
// ---------------------------------------------------------------------------
__global__ void cvt_f32_to_f16_kernel(const float* __restrict__ in,
                                      __half* __restrict__ out,
                                      long n) {
  long i = (long)blockIdx.x * blockDim.x + threadIdx.x;
  long stride = (long)gridDim.x * blockDim.x;
  const float4* p4 = (const float4*)in;
  for (long j = i; j * 8 < n; j += stride) {
    float4 a = p4[j * 2];
    float4 b = p4[j * 2 + 1];
    union { s16x8 v; __half2 h2[4]; } w;
    w.h2[0] = __floats2half2_rn(a.x, a.y);
    w.h2[1] = __floats2half2_rn(a.z, a.w);
    w.h2[2] = __floats2half2_rn(b.x, b.y);
    w.h2[3] = __floats2half2_rn(b.z, b.w);
    *(s16x8*)(out + j * 8) = w.v;
  }
}

// ---------------------------------------------------------------------------
// Dequant 8 int4-in-int32 values -> 8 fp16 weights via bit-trick + pk_fma.
// f16(64+q) = 0x5400 | (q<<4);  w = b*s - (64+z)*s  (one v_pk_fma_f16 / pair)
// Scale/zero are loaded HERE (short live range — do not hoist across MFMA).
// ---------------------------------------------------------------------------
__device__ __forceinline__ void dq_store(const int* __restrict__ qp,
                                         float s, float z,
                                         __half* __restrict__ dst) {
  __half hs = __float2half(s);
  __half2 s2 = __halves2half2(hs, hs);
  __half hc = __float2half(-(64.f + z) * s);
  __half2 c2 = __halves2half2(hc, hc);
  int4 q0 = *(const int4*)qp;
  int4 q1 = *(const int4*)(qp + 4);
  uint32_t b0 = 0x54005400u + ((uint32_t)q0.x << 4) + ((uint32_t)q0.y << 20);
  uint32_t b1 = 0x54005400u + ((uint32_t)q0.z << 4) + ((uint32_t)q0.w << 20);
  uint32_t b2 = 0x54005400u + ((uint32_t)q1.x << 4) + ((uint32_t)q1.y << 20);
  uint32_t b3 = 0x54005400u + ((uint32_t)q1.z << 4) + ((uint32_t)q1.w << 20);
  union { s16x8 v; __half2 h2[4]; } w;
  w.h2[0] = __hfma2(*(__half2*)&b0, s2, c2);
  w.h2[1] = __hfma2(*(__half2*)&b1, s2, c2);
  w.h2[2] = __hfma2(*(__half2*)&b2, s2, c2);
  w.h2[3] = __hfma2(*(__half2*)&b3, s2, c2);
  *(s16x8*)dst = w.v;
}

// ---------------------------------------------------------------------------
// Fused gate+up GEMM: h = silu(x @ Wg^T) * (x @ Wu^T), fp16 MFMA, T2 swizzle.
// Tile: BM=128, BN=128, BK=64. 4 waves, each computes 64x64 per matrix.
// ---------------------------------------------------------------------------
__global__ __launch_bounds__(256, 2)
void gateup_kernel(const __half* __restrict__ Xh,
                   const int* __restrict__ Qg, const int* __restrict__ Qu,
                   const float* __restrict__ Sg, const float* __restrict__ Zg,
                   const float* __restrict__ Su, const float* __restrict__ Zu,
                   __half* __restrict__ Hout,
                   int mblocks) {
  constexpr int H = 4096, I = 11008, G = 32;
  const int bid = blockIdx.x;
  const int nb = bid / mblocks;
  const int mb = bid - nb * mblocks;
  const int m0 = mb * 128, n0 = nb * 128;
  const int tid = threadIdx.x;
  const int lane = tid & 63;
  const int wave = tid >> 6;
  const int wm = (wave >> 1) * 64, wn = (wave & 1) * 64;
  const int l15 = lane & 15, lq = lane >> 4;
  const int rsw = (l15 & 7) << 3;  // read-side swizzle

  __shared__ __half As[128][64];
  __shared__ __half Bgs[128][64];
  __shared__ __half Bus[128][64];

  f32x4 accg[4][4], accu[4][4];
#pragma unroll
  for (int i = 0; i < 4; ++i)
#pragma unroll
    for (int j = 0; j < 4; ++j) {
      accg[i][j] = {0.f, 0.f, 0.f, 0.f};
      accu[i][j] = {0.f, 0.f, 0.f, 0.f};
    }

  const int arow = tid >> 3;                   // 0..31
  const int acol = (tid & 7) * 8;              // logical column (elements)
  const int swcol = acol ^ ((arow & 7) << 3);  // swizzled column

  for (int k0 = 0; k0 < H; k0 += 64) {
    __syncthreads();
    // ---- stage A: global_load_lds, linear LDS dest + swizzled source ----
#pragma unroll
    for (int c = 0; c < 4; ++c) {
      const __half* src = Xh + (size_t)(m0 + c * 32 + arow) * H + (k0 + swcol);
      __half* dst = &As[0][0] + (size_t)(c * 256 + tid) * 8;
      __builtin_amdgcn_global_load_lds((const __attribute__((address_space(1))) void*)src,
                                       (__attribute__((address_space(3))) void*)dst,
                                       16, 0, 0);
    }
    // ---- stage B: load q, dequant (scales loaded inline), swizzled write ----
    const int gidx = k0 >> 7;
#pragma unroll
    for (int it = 0; it < 4; ++it) {
      const int r = it * 32 + arow;
      const int rg = n0 + r;
      dq_store(Qg + (size_t)rg * H + (k0 + acol),
               Sg[rg * G + gidx], Zg[rg * G + gidx], &Bgs[r][swcol]);
      dq_store(Qu + (size_t)rg * H + (k0 + acol),
               Su[rg * G + gidx], Zu[rg * G + gidx], &Bus[r][swcol]);
    }
    __syncthreads();
    // ---- MFMA over BK=64 (two K=32 steps) ----
#pragma unroll
    for (int kk = 0; kk < 2; ++kk) {
      const int cbase = (kk * 32 + lq * 8) ^ rsw;
      f16x8 af[4], bgf[4], buf_[4];
#pragma unroll
      for (int i = 0; i < 4; ++i)
        af[i] = *(const f16x8*)&As[wm + i * 16 + l15][cbase];
#pragma unroll
      for (int j = 0; j < 4; ++j) {
        bgf[j]  = *(const f16x8*)&Bgs[wn + j * 16 + l15][cbase];
        buf_[j] = *(const f16x8*)&Bus[wn + j * 16 + l15][cbase];
      }
#pragma unroll
      for (int i = 0; i < 4; ++i)
#pragma unroll
        for (int j = 0; j < 4; ++j) {
          accg[i][j] = __builtin_amdgcn_mfma_f32_16x16x32_f16(af[i], bgf[j], accg[i][j], 0, 0, 0);
          accu[i][j] = __builtin_amdgcn_mfma_f32_16x16x32_f16(af[i], buf_[j], accu[i][j], 0, 0, 0);
        }
    }
  }
  // ---- epilogue: h = silu(g)*u -> fp16 ----
#pragma unroll
  for (int i = 0; i < 4; ++i)
#pragma unroll
    for (int j = 0; j < 4; ++j)
#pragma unroll
      for (int r = 0; r < 4; ++r) {
        const int row = m0 + wm + i * 16 + lq * 4 + r;
        const int col = n0 + wn + j * 16 + l15;
        float g = accg[i][j][r];
        float u = accu[i][j][r];
        float hv = (g / (1.f + __expf(-g))) * u;
        Hout[(size_t)row * I + col] = __float2half(hv);
      }
}

// ---------------------------------------------------------------------------
// Down GEMM: out = h @ Wd^T. fp16 MFMA, T2 swizzle. K=11008.
// ---------------------------------------------------------------------------
__global__ __launch_bounds__(256, 2)
void down_kernel(const __half* __restrict__ Hin,
                 const int* __restrict__ Qd,
                 const float* __restrict__ Sd, const float* __restrict__ Zd,
                 float* __restrict__ Out,
                 int mblocks) {
  constexpr int K = 11008, N = 4096, G = 86;
  const int bid = blockIdx.x;
  const int nb = bid / mblocks;
  const int mb = bid - nb * mblocks;
  const int m0 = mb * 128, n0 = nb * 128;
  const int tid = threadIdx.x;
  const int lane = tid & 63;
  const int wave = tid >> 6;
  const int wm = (wave >> 1) * 64, wn = (wave & 1) * 64;
  const int l15 = lane & 15, lq = lane >> 4;
  const int rsw = (l15 & 7) << 3;

  __shared__ __half As[128][64];
  __shared__ __half Bs[128][64];

  f32x4 acc[4][4];
#pragma unroll
  for (int i = 0; i < 4; ++i)
#pragma unroll
    for (int j = 0; j < 4; ++j) acc[i][j] = {0.f, 0.f, 0.f, 0.f};

  const int arow = tid >> 3;
  const int acol = (tid & 7) * 8;
  const int swcol = acol ^ ((arow & 7) << 3);

  for (int k0 = 0; k0 < K; k0 += 64) {
    __syncthreads();
#pragma unroll
    for (int c = 0; c < 4; ++c) {
      const __half* src = Hin + (size_t)(m0 + c * 32 + arow) * K + (k0 + swcol);
      __half* dst = &As[0][0] + (size_t)(c * 256 + tid) * 8;
      __builtin_amdgcn_global_load_lds((const __attribute__((address_space(1))) void*)src,
                                       (__attribute__((address_space(3))) void*)dst,
                                       16, 0, 0);
    }
    const int gidx = k0 >> 7;
#pragma unroll
    for (int it = 0; it < 4; ++it) {
      const int r = it * 32 + arow;
      const int rg = n0 + r;
      dq_store(Qd + (size_t)rg * K + (k0 + acol),
               Sd[rg * G + gidx], Zd[rg * G + gidx], &Bs[r][swcol]);
    }
    __syncthreads();
#pragma unroll
    for (int kk = 0; kk < 2; ++kk) {
      const int cbase = (kk * 32 + lq * 8) ^ rsw;
      f16x8 af[4], bf[4];
#pragma unroll
      for (int i = 0; i < 4; ++i)
        af[i] = *(const f16x8*)&As[wm + i * 16 + l15][cbase];
#pragma unroll
      for (int j = 0; j < 4; ++j)
        bf[j] = *(const f16x8*)&Bs[wn + j * 16 + l15][cbase];
#pragma unroll
      for (int i = 0; i < 4; ++i)
#pragma unroll
        for (int j = 0; j < 4; ++j)
          acc[i][j] = __builtin_amdgcn_mfma_f32_16x16x32_f16(af[i], bf[j], acc[i][j], 0, 0, 0);
    }
  }
#pragma unroll
  for (int i = 0; i < 4; ++i)
#pragma unroll
    for (int j = 0; j < 4; ++j)
#pragma unroll
      for (int r = 0; r < 4; ++r) {
        const int row = m0 + wm + i * 16 + lq * 4 + r;
        const int col = n0 + wn + j * 16 + l15;
        Out[(size_t)row * N + col] = acc[i][j][r];
      }
}

// ---------------------------------------------------------------------------
extern "C" void kernel_launch(void* const* d_in, const int* in_sizes, int n_in,
                              void* d_out, int out_size, void* d_ws, size_t ws_size,
                              hipStream_t stream) {
  const float* x  = (const float*)d_in[0];
  const int* qg   = (const int*)d_in[1];
  const int* qu   = (const int*)d_in[2];
  const int* qd   = (const int*)d_in[3];
  const float* sg = (const float*)d_in[4];
  const float* zg = (const float*)d_in[5];
  const float* su = (const float*)d_in[6];
  const float* zu = (const float*)d_in[7];
  const float* sd = (const float*)d_in[8];
  const float* zd = (const float*)d_in[9];
  float* out = (float*)d_out;

  const int M = 4 * 2048, H = 4096, I = 11008;

  const size_t per_row = (size_t)(H + I) * 2;
  long mc = (long)(ws_size / per_row);
  mc &= ~127L;
  if (mc > M) mc = M;
  if (mc < 128) mc = 128;
  const int Mc = (int)mc;

  __half* wsx = (__half*)d_ws;
  __half* wsh = (__half*)((char*)d_ws + (size_t)Mc * H * 2);

  for (int mbase = 0; mbase < M; mbase += Mc) {
    const int rows = (M - mbase < Mc) ? (M - mbase) : Mc;
    const int mblocks = rows / 128;
    const long n = (long)rows * H;
    cvt_f32_to_f16_kernel<<<1024, 256, 0, stream>>>(x + (size_t)mbase * H, wsx, n);
    gateup_kernel<<<(I / 128) * mblocks, 256, 0, stream>>>(
        wsx, qg, qu, sg, zg, su, zu, wsh, mblocks);
    down_kernel<<<(H / 128) * mblocks, 256, 0, stream>>>(
        wsh, qd, sd, zd, out + (size_t)mbase * H, mblocks);
  }
}